// Round 3
// baseline (813.988 us; speedup 1.0000x reference)
//
#include <hip/hip_runtime.h>

typedef unsigned short ushort_t;
typedef __bf16 bf16x8 __attribute__((ext_vector_type(8)));
typedef float f32x4 __attribute__((ext_vector_type(4)));
typedef short short8 __attribute__((ext_vector_type(8)));

__device__ __forceinline__ float bf2f(unsigned short u) {
    union { unsigned int i; float f; } v; v.i = ((unsigned int)u) << 16; return v.f;
}
__device__ __forceinline__ unsigned short f2bf(float f) {
    union { float f; unsigned int i; } v; v.f = f;
    unsigned int r = v.i + 0x7fffu + ((v.i >> 16) & 1u);
    return (unsigned short)(r >> 16);
}
__device__ __forceinline__ float sigm(float x) { return 1.0f / (1.0f + __expf(-x)); }

__device__ __forceinline__ void async_copy16(const ushort_t* src, ushort_t* dst_lds) {
    __builtin_amdgcn_global_load_lds(
        (const __attribute__((address_space(1))) void*)src,
        (__attribute__((address_space(3))) void*)dst_lds,
        16, 0, 0);
}

// ---- param conversion: 5 W (768x768) + 5 bias (768) + ts (768), f32 -> bf16, fixed layout ----
#define WSEG 589824           // 768*768
#define NWALL 2949120         // 5*WSEG
#define NTOT 2953728          // + 6*768
__global__ __launch_bounds__(256)
void convert_params(const float* __restrict__ Wq, const float* __restrict__ Wk,
                    const float* __restrict__ Wv, const float* __restrict__ Wg1,
                    const float* __restrict__ Wg2, const float* __restrict__ bq,
                    const float* __restrict__ bk, const float* __restrict__ bv,
                    const float* __restrict__ bg1, const float* __restrict__ bg2,
                    const float* __restrict__ ts, ushort_t* __restrict__ dst)
{
    int i = (blockIdx.x * 256 + threadIdx.x) * 8;
    if (i >= NTOT) return;
    const float* src; int off;
    if (i < NWALL) {
        int wi = i / WSEG; off = i - wi * WSEG;
        src = (wi == 0) ? Wq : (wi == 1) ? Wk : (wi == 2) ? Wv : (wi == 3) ? Wg1 : Wg2;
    } else {
        int j = i - NWALL; int bi = j / 768; off = j - bi * 768;
        src = (bi == 0) ? bq : (bi == 1) ? bk : (bi == 2) ? bv : (bi == 3) ? bg1 : (bi == 4) ? bg2 : ts;
    }
    float4 a = *(const float4*)(src + off);
    float4 b = *(const float4*)(src + off + 4);
    short8 o;
    o[0] = (short)f2bf(a.x); o[1] = (short)f2bf(a.y); o[2] = (short)f2bf(a.z); o[3] = (short)f2bf(a.w);
    o[4] = (short)f2bf(b.x); o[5] = (short)f2bf(b.y); o[6] = (short)f2bf(b.z); o[7] = (short)f2bf(b.w);
    *(short8*)(dst + i) = o;
}

// C[M,N] = A[M,K] @ B[N,K]^T (+ epilogue). B always bf16. M%128==0, N%128==0, K%32==0.
// AF32: A operand is f32 (reg-staged + cvt); else bf16 (global_load_lds).
// CF32: store f32; else bf16.
// EPI: 0=plain, 1=+bias, 2=*scale, 3=+bias+relu, 4=gate: sigmoid(sigmoid(x+bias))*aux*ts (aux f32)
template<int EPI, int AF32, int CF32>
__global__ __launch_bounds__(256, 2)
void gemm_bt(const void* __restrict__ Av, const ushort_t* __restrict__ B,
             void* __restrict__ Cv, const ushort_t* __restrict__ bias,
             const float* __restrict__ aux, const ushort_t* __restrict__ ts,
             int M, int N, int K, float scale)
{
    __shared__ __align__(16) ushort_t As[128 * 32];
    __shared__ __align__(16) ushort_t Bs[128 * 32];
    const int tid  = threadIdx.x;
    const int lane = tid & 63;
    const int wave = tid >> 6;
    const int wr = wave >> 1, wc = wave & 1;
    const int row0 = blockIdx.y * 128;
    const int col0 = blockIdx.x * 128;

    f32x4 acc[4][4] = {};

    // bf16 staging: 256 threads x 16B = 64 rows of 32 bf16 per inst
    const int srow = tid >> 2;
    const int scol = (tid & 3) * 8;
    const ushort_t* ga0 = (const ushort_t*)Av + (size_t)(row0 + srow) * K + scol;
    const ushort_t* gb0 = B + (size_t)(col0 + srow) * K + scol;
    // f32-A staging: thread t -> row t>>1, col half (t&1)*16; 16 f32 per thread
    const int arow_s = tid >> 1;
    const int acol_s = (tid & 1) * 16;
    const float* gaf = (const float*)Av + (size_t)(row0 + arow_s) * K + acol_s;

    const int kop  = (lane >> 4) * 8;
    const int arow = wr * 64 + (lane & 15);
    const int brow = wc * 64 + (lane & 15);

    for (int k0 = 0; k0 < K; k0 += 32) {
        if (AF32) {
            float4 fa0 = *(const float4*)(gaf + k0);
            float4 fa1 = *(const float4*)(gaf + k0 + 4);
            float4 fa2 = *(const float4*)(gaf + k0 + 8);
            float4 fa3 = *(const float4*)(gaf + k0 + 12);
            async_copy16(gb0 + k0,                  Bs + tid * 8);
            async_copy16(gb0 + (size_t)64 * K + k0, Bs + 2048 + tid * 8);
            short8 p0, p1;
            p0[0] = (short)f2bf(fa0.x); p0[1] = (short)f2bf(fa0.y);
            p0[2] = (short)f2bf(fa0.z); p0[3] = (short)f2bf(fa0.w);
            p0[4] = (short)f2bf(fa1.x); p0[5] = (short)f2bf(fa1.y);
            p0[6] = (short)f2bf(fa1.z); p0[7] = (short)f2bf(fa1.w);
            p1[0] = (short)f2bf(fa2.x); p1[1] = (short)f2bf(fa2.y);
            p1[2] = (short)f2bf(fa2.z); p1[3] = (short)f2bf(fa2.w);
            p1[4] = (short)f2bf(fa3.x); p1[5] = (short)f2bf(fa3.y);
            p1[6] = (short)f2bf(fa3.z); p1[7] = (short)f2bf(fa3.w);
            *(short8*)(As + arow_s * 32 + acol_s)     = p0;
            *(short8*)(As + arow_s * 32 + acol_s + 8) = p1;
        } else {
            async_copy16(ga0 + k0,                  As + tid * 8);
            async_copy16(ga0 + (size_t)64 * K + k0, As + 2048 + tid * 8);
            async_copy16(gb0 + k0,                  Bs + tid * 8);
            async_copy16(gb0 + (size_t)64 * K + k0, Bs + 2048 + tid * 8);
        }
        asm volatile("s_waitcnt vmcnt(0)" ::: "memory");
        __syncthreads();

        bf16x8 af[4], bfr[4];
        #pragma unroll
        for (int m = 0; m < 4; ++m)
            af[m] = *(const bf16x8*)(As + (arow + m * 16) * 32 + kop);
        #pragma unroll
        for (int n = 0; n < 4; ++n)
            bfr[n] = *(const bf16x8*)(Bs + (brow + n * 16) * 32 + kop);
        #pragma unroll
        for (int m = 0; m < 4; ++m)
            #pragma unroll
            for (int n = 0; n < 4; ++n)
                acc[m][n] = __builtin_amdgcn_mfma_f32_16x16x32_bf16(af[m], bfr[n], acc[m][n], 0, 0, 0);
        __syncthreads();
    }

    // epilogue: C/D layout col=lane&15, row=(lane>>4)*4+reg
    const int r0 = row0 + wr * 64 + (lane >> 4) * 4;
    const int c0 = col0 + wc * 64 + (lane & 15);
    #pragma unroll
    for (int m = 0; m < 4; ++m) {
        #pragma unroll
        for (int n = 0; n < 4; ++n) {
            const int col = c0 + n * 16;
            #pragma unroll
            for (int r = 0; r < 4; ++r) {
                const int row = r0 + m * 16 + r;
                float val = acc[m][n][r];
                if (EPI == 1) {
                    val += bf2f(bias[col]);
                } else if (EPI == 2) {
                    val *= scale;
                } else if (EPI == 3) {
                    val += bf2f(bias[col]);
                    val = fmaxf(val, 0.0f);
                } else if (EPI == 4) {
                    val += bf2f(bias[col]);
                    float g  = sigm(val);
                    float gg = sigm(g);
                    val = gg * aux[(size_t)row * N + col] * bf2f(ts[col]);
                }
                if (CF32) ((float*)Cv)[(size_t)row * N + col] = val;
                else      ((ushort_t*)Cv)[(size_t)row * N + col] = f2bf(val);
            }
        }
    }
}

// in-place row softmax: P is [rows][S] bf16, one block (256 thr) per row, S=2048
__global__ __launch_bounds__(256)
void softmax_inplace(ushort_t* __restrict__ P, int S)
{
    const size_t row = blockIdx.x;
    ushort_t* p = P + row * (size_t)S;
    const int tid = threadIdx.x;
    const int lane = tid & 63, wave = tid >> 6;

    short8 raw = *(const short8*)(p + tid * 8);
    float x[8];
    #pragma unroll
    for (int j = 0; j < 8; ++j) x[j] = bf2f((unsigned short)raw[j]);

    float mx = x[0];
    #pragma unroll
    for (int j = 1; j < 8; ++j) mx = fmaxf(mx, x[j]);
    #pragma unroll
    for (int o = 32; o > 0; o >>= 1) mx = fmaxf(mx, __shfl_xor(mx, o));
    __shared__ float redm[4], reds[4];
    if (lane == 0) redm[wave] = mx;
    __syncthreads();
    mx = fmaxf(fmaxf(redm[0], redm[1]), fmaxf(redm[2], redm[3]));

    float s = 0.f;
    #pragma unroll
    for (int j = 0; j < 8; ++j) { x[j] = __expf(x[j] - mx); s += x[j]; }
    #pragma unroll
    for (int o = 32; o > 0; o >>= 1) s += __shfl_xor(s, o);
    if (lane == 0) reds[wave] = s;
    __syncthreads();
    s = reds[0] + reds[1] + reds[2] + reds[3];
    const float inv = 1.0f / s;

    short8 outv;
    #pragma unroll
    for (int j = 0; j < 8; ++j) outv[j] = (short)f2bf(x[j] * inv);
    *(short8*)(p + tid * 8) = outv;
}

// VT[z][c][r] = V[z][r][c];  grid (C/32, R/32, Z), block (32,8). bf16.
__global__ __launch_bounds__(256)
void transpose2d(const ushort_t* __restrict__ V, ushort_t* __restrict__ VT, int R, int Ccols)
{
    __shared__ ushort_t t[32][33];
    const size_t zoff = (size_t)blockIdx.z * R * Ccols;
    const int tx = threadIdx.x, ty = threadIdx.y;
    const int c = blockIdx.x * 32 + tx;
    const int rbase = blockIdx.y * 32;
    #pragma unroll
    for (int i = 0; i < 4; ++i)
        t[ty + i * 8][tx] = V[zoff + (size_t)(rbase + ty + i * 8) * Ccols + c];
    __syncthreads();
    const int r = rbase + tx;
    const int cbase = blockIdx.x * 32;
    #pragma unroll
    for (int i = 0; i < 4; ++i)
        VT[zoff + (size_t)(cbase + ty + i * 8) * R + r] = t[tx][ty + i * 8];
}

extern "C" void kernel_launch(void* const* d_in, const int* in_sizes, int n_in,
                              void* d_out, int out_size, void* d_ws, size_t ws_size,
                              hipStream_t stream)
{
    (void)in_sizes; (void)n_in; (void)out_size; (void)ws_size;
    const float* query = (const float*)d_in[0];
    const float* key_  = (const float*)d_in[1];
    const float* value = (const float*)d_in[2];
    const float* Wq  = (const float*)d_in[3];
    const float* bq  = (const float*)d_in[4];
    const float* Wk  = (const float*)d_in[5];
    const float* bk  = (const float*)d_in[6];
    const float* Wv  = (const float*)d_in[7];
    const float* bv  = (const float*)d_in[8];
    const float* Wg1 = (const float*)d_in[9];
    const float* bg1 = (const float*)d_in[10];
    const float* Wg2 = (const float*)d_in[11];
    const float* bg2 = (const float*)d_in[12];
    const float* tsc = (const float*)d_in[13];

    const int S = 2048, D = 768, Bc = 8;
    const int MS = Bc * S;                  // 16384
    const long long SD = (long long)S * D;  // elems per batch

    // ws layout (bytes), ~90MB total:
    //   q@0 (25.2M), k@25.2M, vT@50.3M, Wb@75.5M (5.9M), P@81.4M (8.4M)
    char* ws = (char*)d_ws;
    ushort_t* q   = (ushort_t*)(ws);
    ushort_t* k   = (ushort_t*)(ws + 25165824ll);
    ushort_t* vT  = (ushort_t*)(ws + 50331648ll);
    ushort_t* Wb  = (ushort_t*)(ws + 75497472ll);
    ushort_t* P   = (ushort_t*)(ws + 81404928ll);
    ushort_t* h   = k;                      // k dead after scores
    // d_out (50.3MB f32): first 25.2MB holds bf16 v until transpose; then f32 att; then final out in-place
    ushort_t* v    = (ushort_t*)d_out;
    float*    attf = (float*)d_out;

    // bf16 param offsets within Wb (elems)
    const int WQ = 0, WK = 589824, WV = 1179648, WG1 = 1769472, WG2 = 2359296;
    const int BQ = 2949120, BK = 2949888, BV = 2950656, BG1 = 2951424, BG2 = 2952192, TSO = 2952960;

    const dim3 blk(256);
    const float scale = 0.03608439182435161f; // 1/sqrt(768)

    // 0. convert params to bf16
    convert_params<<<dim3((NTOT / 8 + 255) / 256), blk, 0, stream>>>(
        Wq, Wk, Wv, Wg1, Wg2, bq, bk, bv, bg1, bg2, tsc, Wb);
    // 1. projections (A = f32 inputs)
    gemm_bt<1, 1, 0><<<dim3(D / 128, MS / 128), blk, 0, stream>>>(query, Wb + WQ, q, Wb + BQ, nullptr, nullptr, MS, D, D, 1.f);
    gemm_bt<1, 1, 0><<<dim3(D / 128, MS / 128), blk, 0, stream>>>(key_,  Wb + WK, k, Wb + BK, nullptr, nullptr, MS, D, D, 1.f);
    gemm_bt<1, 1, 0><<<dim3(D / 128, MS / 128), blk, 0, stream>>>(value, Wb + WV, v, Wb + BV, nullptr, nullptr, MS, D, D, 1.f);
    // 2. vT = transpose(v) per batch; v (front of d_out) dead afterwards
    transpose2d<<<dim3(D / 32, S / 32, Bc), dim3(32, 8), 0, stream>>>(v, vT, S, D);
    // 3-5. per-batch attention
    for (int z = 0; z < Bc; ++z) {
        gemm_bt<2, 0, 0><<<dim3(S / 128, S / 128), blk, 0, stream>>>(q + (size_t)z * SD, k + (size_t)z * SD, P,
                                                                      nullptr, nullptr, nullptr, S, S, D, scale);
        softmax_inplace<<<dim3(S), blk, 0, stream>>>(P, S);
        gemm_bt<0, 0, 1><<<dim3(D / 128, S / 128), blk, 0, stream>>>(P, vT + (size_t)z * SD, attf + (size_t)z * SD,
                                                                      nullptr, nullptr, nullptr, S, D, S, 1.f);
    }
    // 6. h = relu(att @ Wg1^T + bg1)  (A = f32 att in d_out; h overlays k)
    gemm_bt<3, 1, 0><<<dim3(D / 128, MS / 128), blk, 0, stream>>>(attf, Wb + WG1, h, Wb + BG1, nullptr, nullptr, MS, D, D, 1.f);
    // 7. out = sigmoid(sigmoid(h @ Wg2^T + bg2)) * att * ts  (f32 in-place over d_out, per-element RAW-safe)
    gemm_bt<4, 0, 1><<<dim3(D / 128, MS / 128), blk, 0, stream>>>(h, Wb + WG2, d_out, Wb + BG2, attf, Wb + TSO, MS, D, D, 1.f);
}

// Round 4
// 374.653 us; speedup vs baseline: 2.1726x; 2.1726x over previous
//
#include <hip/hip_runtime.h>

typedef unsigned short ushort_t;
typedef __bf16 bf16x8 __attribute__((ext_vector_type(8)));
typedef float f32x4 __attribute__((ext_vector_type(4)));
typedef short short8 __attribute__((ext_vector_type(8)));

__device__ __forceinline__ float bf2f(unsigned short u) {
    union { unsigned int i; float f; } v; v.i = ((unsigned int)u) << 16; return v.f;
}
__device__ __forceinline__ unsigned short f2bf(float f) {
    union { float f; unsigned int i; } v; v.f = f;
    unsigned int r = v.i + 0x7fffu + ((v.i >> 16) & 1u);
    return (unsigned short)(r >> 16);
}
__device__ __forceinline__ float sigm(float x) { return 1.0f / (1.0f + __expf(-x)); }

__device__ __forceinline__ void async_copy16(const ushort_t* src, ushort_t* dst_lds) {
    __builtin_amdgcn_global_load_lds(
        (const __attribute__((address_space(1))) void*)src,
        (__attribute__((address_space(3))) void*)dst_lds,
        16, 0, 0);
}

// ---- param conversion: 5 W (768x768) + 5 bias (768) + ts (768), f32 -> bf16, fixed layout ----
#define WSEG 589824           // 768*768
#define NWALL 2949120         // 5*WSEG
#define NTOT 2953728          // + 6*768
__global__ __launch_bounds__(256)
void convert_params(const float* __restrict__ Wq, const float* __restrict__ Wk,
                    const float* __restrict__ Wv, const float* __restrict__ Wg1,
                    const float* __restrict__ Wg2, const float* __restrict__ bq,
                    const float* __restrict__ bk, const float* __restrict__ bv,
                    const float* __restrict__ bg1, const float* __restrict__ bg2,
                    const float* __restrict__ ts, ushort_t* __restrict__ dst)
{
    int i = (blockIdx.x * 256 + threadIdx.x) * 8;
    if (i >= NTOT) return;
    const float* src; int off;
    if (i < NWALL) {
        int wi = i / WSEG; off = i - wi * WSEG;
        src = (wi == 0) ? Wq : (wi == 1) ? Wk : (wi == 2) ? Wv : (wi == 3) ? Wg1 : Wg2;
    } else {
        int j = i - NWALL; int bi = j / 768; off = j - bi * 768;
        src = (bi == 0) ? bq : (bi == 1) ? bk : (bi == 2) ? bv : (bi == 3) ? bg1 : (bi == 4) ? bg2 : ts;
    }
    float4 a = *(const float4*)(src + off);
    float4 b = *(const float4*)(src + off + 4);
    short8 o;
    o[0] = (short)f2bf(a.x); o[1] = (short)f2bf(a.y); o[2] = (short)f2bf(a.z); o[3] = (short)f2bf(a.w);
    o[4] = (short)f2bf(b.x); o[5] = (short)f2bf(b.y); o[6] = (short)f2bf(b.z); o[7] = (short)f2bf(b.w);
    *(short8*)(dst + i) = o;
}

// C[M,N] = A[M,K] @ B[N,K]^T (+ epilogue), optionally batched via (batchA,batchB,batchC)
// with batch index folded into the (XCD-swizzled) flat block id. M = rows PER BATCH.
// B always bf16. AF32: A operand f32 (reg-staged + cvt); else bf16 (global_load_lds).
// CF32: store f32; else bf16. aux (EPI=4) is bf16.
// EPI: 0=plain, 1=+bias, 2=*scale, 3=+bias+relu, 4=gate: sigmoid(sigmoid(x+bias))*aux*ts
// Requires gridDim.x*gridDim.y*gridDim.z % 8 == 0.
template<int EPI, int AF32, int CF32>
__global__ __launch_bounds__(256, 2)
void gemm_bt(const void* __restrict__ Av, const ushort_t* __restrict__ B,
             void* __restrict__ Cv, const ushort_t* __restrict__ bias,
             const ushort_t* __restrict__ aux, const ushort_t* __restrict__ ts,
             int M, int N, int K, float scale,
             long long batchA, long long batchB, long long batchC)
{
    __shared__ __align__(16) ushort_t As[128 * 32];
    __shared__ __align__(16) ushort_t Bs[128 * 32];
    const int tid  = threadIdx.x;
    const int lane = tid & 63;
    const int wave = tid >> 6;
    const int wr = wave >> 1, wc = wave & 1;

    // XCD-aware bijective swizzle over the full flat grid (nwg % 8 == 0)
    const int gx = gridDim.x, gy = gridDim.y;
    const int nwg = gx * gy * gridDim.z;
    int fid = (blockIdx.z * gy + blockIdx.y) * gx + blockIdx.x;
    fid = (fid & 7) * (nwg >> 3) + (fid >> 3);
    const int bz  = fid / (gx * gy);
    const int rem = fid - bz * (gx * gy);
    const int by  = rem / gx;
    const int bx  = rem - by * gx;
    const int row0 = by * 128;
    const int col0 = bx * 128;

    f32x4 acc[4][4] = {};

    // bf16 staging: 256 threads x 16B = 64 rows of 32 bf16 per inst
    const int srow = tid >> 2;
    const int scol = (tid & 3) * 8;
    const ushort_t* ga0 = (const ushort_t*)Av + batchA * bz + (size_t)(row0 + srow) * K + scol;
    const ushort_t* gb0 = B + batchB * bz + (size_t)(col0 + srow) * K + scol;
    // f32-A staging: thread t -> row t>>1, col half (t&1)*16; 16 f32 per thread
    const int arow_s = tid >> 1;
    const int acol_s = (tid & 1) * 16;
    const float* gaf = (const float*)Av + batchA * bz + (size_t)(row0 + arow_s) * K + acol_s;

    const int kop  = (lane >> 4) * 8;
    const int arow = wr * 64 + (lane & 15);
    const int brow = wc * 64 + (lane & 15);

    for (int k0 = 0; k0 < K; k0 += 32) {
        if (AF32) {
            float4 fa0 = *(const float4*)(gaf + k0);
            float4 fa1 = *(const float4*)(gaf + k0 + 4);
            float4 fa2 = *(const float4*)(gaf + k0 + 8);
            float4 fa3 = *(const float4*)(gaf + k0 + 12);
            async_copy16(gb0 + k0,                  Bs + tid * 8);
            async_copy16(gb0 + (size_t)64 * K + k0, Bs + 2048 + tid * 8);
            short8 p0, p1;
            p0[0] = (short)f2bf(fa0.x); p0[1] = (short)f2bf(fa0.y);
            p0[2] = (short)f2bf(fa0.z); p0[3] = (short)f2bf(fa0.w);
            p0[4] = (short)f2bf(fa1.x); p0[5] = (short)f2bf(fa1.y);
            p0[6] = (short)f2bf(fa1.z); p0[7] = (short)f2bf(fa1.w);
            p1[0] = (short)f2bf(fa2.x); p1[1] = (short)f2bf(fa2.y);
            p1[2] = (short)f2bf(fa2.z); p1[3] = (short)f2bf(fa2.w);
            p1[4] = (short)f2bf(fa3.x); p1[5] = (short)f2bf(fa3.y);
            p1[6] = (short)f2bf(fa3.z); p1[7] = (short)f2bf(fa3.w);
            *(short8*)(As + arow_s * 32 + acol_s)     = p0;
            *(short8*)(As + arow_s * 32 + acol_s + 8) = p1;
        } else {
            async_copy16(ga0 + k0,                  As + tid * 8);
            async_copy16(ga0 + (size_t)64 * K + k0, As + 2048 + tid * 8);
            async_copy16(gb0 + k0,                  Bs + tid * 8);
            async_copy16(gb0 + (size_t)64 * K + k0, Bs + 2048 + tid * 8);
        }
        asm volatile("s_waitcnt vmcnt(0)" ::: "memory");
        __syncthreads();

        bf16x8 af[4], bfr[4];
        #pragma unroll
        for (int m = 0; m < 4; ++m)
            af[m] = *(const bf16x8*)(As + (arow + m * 16) * 32 + kop);
        #pragma unroll
        for (int n = 0; n < 4; ++n)
            bfr[n] = *(const bf16x8*)(Bs + (brow + n * 16) * 32 + kop);
        #pragma unroll
        for (int m = 0; m < 4; ++m)
            #pragma unroll
            for (int n = 0; n < 4; ++n)
                acc[m][n] = __builtin_amdgcn_mfma_f32_16x16x32_bf16(af[m], bfr[n], acc[m][n], 0, 0, 0);
        __syncthreads();
    }

    // epilogue: C/D layout col=lane&15, row=(lane>>4)*4+reg
    const int r0 = row0 + wr * 64 + (lane >> 4) * 4;
    const int c0 = col0 + wc * 64 + (lane & 15);
    #pragma unroll
    for (int m = 0; m < 4; ++m) {
        #pragma unroll
        for (int n = 0; n < 4; ++n) {
            const int col = c0 + n * 16;
            #pragma unroll
            for (int r = 0; r < 4; ++r) {
                const int row = r0 + m * 16 + r;
                float val = acc[m][n][r];
                if (EPI == 1) {
                    val += bf2f(bias[col]);
                } else if (EPI == 2) {
                    val *= scale;
                } else if (EPI == 3) {
                    val += bf2f(bias[col]);
                    val = fmaxf(val, 0.0f);
                } else if (EPI == 4) {
                    val += bf2f(bias[col]);
                    float g  = sigm(val);
                    float gg = sigm(g);
                    val = gg * bf2f(aux[(size_t)row * N + col]) * bf2f(ts[col]);
                }
                if (CF32) ((float*)Cv)[batchC * bz + (size_t)row * N + col] = val;
                else      ((ushort_t*)Cv)[batchC * bz + (size_t)row * N + col] = f2bf(val);
            }
        }
    }
}

// in-place row softmax: P is [rows][S] bf16, one block (256 thr) per row, S=2048
__global__ __launch_bounds__(256)
void softmax_inplace(ushort_t* __restrict__ P, int S)
{
    const size_t row = blockIdx.x;
    ushort_t* p = P + row * (size_t)S;
    const int tid = threadIdx.x;
    const int lane = tid & 63, wave = tid >> 6;

    short8 raw = *(const short8*)(p + tid * 8);
    float x[8];
    #pragma unroll
    for (int j = 0; j < 8; ++j) x[j] = bf2f((unsigned short)raw[j]);

    float mx = x[0];
    #pragma unroll
    for (int j = 1; j < 8; ++j) mx = fmaxf(mx, x[j]);
    #pragma unroll
    for (int o = 32; o > 0; o >>= 1) mx = fmaxf(mx, __shfl_xor(mx, o));
    __shared__ float redm[4], reds[4];
    if (lane == 0) redm[wave] = mx;
    __syncthreads();
    mx = fmaxf(fmaxf(redm[0], redm[1]), fmaxf(redm[2], redm[3]));

    float s = 0.f;
    #pragma unroll
    for (int j = 0; j < 8; ++j) { x[j] = __expf(x[j] - mx); s += x[j]; }
    #pragma unroll
    for (int o = 32; o > 0; o >>= 1) s += __shfl_xor(s, o);
    if (lane == 0) reds[wave] = s;
    __syncthreads();
    s = reds[0] + reds[1] + reds[2] + reds[3];
    const float inv = 1.0f / s;

    short8 outv;
    #pragma unroll
    for (int j = 0; j < 8; ++j) outv[j] = (short)f2bf(x[j] * inv);
    *(short8*)(p + tid * 8) = outv;
}

// VT[z][c][r] = V[z][r][c];  grid (C/32, R/32, Z), block (32,8). bf16.
__global__ __launch_bounds__(256)
void transpose2d(const ushort_t* __restrict__ V, ushort_t* __restrict__ VT, int R, int Ccols)
{
    __shared__ ushort_t t[32][33];
    const size_t zoff = (size_t)blockIdx.z * R * Ccols;
    const int tx = threadIdx.x, ty = threadIdx.y;
    const int c = blockIdx.x * 32 + tx;
    const int rbase = blockIdx.y * 32;
    #pragma unroll
    for (int i = 0; i < 4; ++i)
        t[ty + i * 8][tx] = V[zoff + (size_t)(rbase + ty + i * 8) * Ccols + c];
    __syncthreads();
    const int r = rbase + tx;
    const int cbase = blockIdx.x * 32;
    #pragma unroll
    for (int i = 0; i < 4; ++i)
        VT[zoff + (size_t)(cbase + ty + i * 8) * R + r] = t[tx][ty + i * 8];
}

extern "C" void kernel_launch(void* const* d_in, const int* in_sizes, int n_in,
                              void* d_out, int out_size, void* d_ws, size_t ws_size,
                              hipStream_t stream)
{
    (void)in_sizes; (void)n_in; (void)out_size;
    const float* query = (const float*)d_in[0];
    const float* key_  = (const float*)d_in[1];
    const float* value = (const float*)d_in[2];
    const float* Wq  = (const float*)d_in[3];
    const float* bq  = (const float*)d_in[4];
    const float* Wk  = (const float*)d_in[5];
    const float* bk  = (const float*)d_in[6];
    const float* Wv  = (const float*)d_in[7];
    const float* bv  = (const float*)d_in[8];
    const float* Wg1 = (const float*)d_in[9];
    const float* bg1 = (const float*)d_in[10];
    const float* Wg2 = (const float*)d_in[11];
    const float* bg2 = (const float*)d_in[12];
    const float* tsc = (const float*)d_in[13];

    const int S = 2048, D = 768, Bc = 8;
    const int MS = Bc * S;                     // 16384
    const long long SD = (long long)S * D;     // 1,572,864 elems per batch
    const long long SS = (long long)S * S;     // 4,194,304 elems per batch

    // ws layout (bytes):
    //   q/att @0 (25.2M) | k/h @25.2M (25.2M) | vT @50.3M (25.2M) | Wb @75.5M (5.9M) | P @81.4M
    // P per-batch: 8.4M (total 89.8M, proven fits); P batched: 67.1M (total 148.5M, used if ws allows)
    char* ws = (char*)d_ws;
    ushort_t* q   = (ushort_t*)(ws);
    ushort_t* att = q;                         // PV(z) overwrites q(z) after scores(z) consumed it
    ushort_t* k   = (ushort_t*)(ws + 25165824ll);
    ushort_t* h   = k;                         // k dead after scores
    ushort_t* vT  = (ushort_t*)(ws + 50331648ll);
    ushort_t* Wb  = (ushort_t*)(ws + 75497472ll);
    ushort_t* P   = (ushort_t*)(ws + 81404928ll);
    ushort_t* v   = (ushort_t*)d_out;          // bf16 v in front half of d_out until transpose

    const int WQ = 0, WK = 589824, WV = 1179648, WG1 = 1769472, WG2 = 2359296;
    const int BQ = 2949120, BK = 2949888, BV = 2950656, BG1 = 2951424, BG2 = 2952192, TSO = 2952960;

    const dim3 blk(256);
    const float scale = 0.03608439182435161f; // 1/sqrt(768)
    const bool batched = ws_size >= 148513792ull;

    // 0. convert params to bf16
    convert_params<<<dim3((NTOT / 8 + 255) / 256), blk, 0, stream>>>(
        Wq, Wk, Wv, Wg1, Wg2, bq, bk, bv, bg1, bg2, tsc, Wb);
    // 1. projections (A = f32 inputs)
    gemm_bt<1, 1, 0><<<dim3(D / 128, MS / 128), blk, 0, stream>>>(query, Wb + WQ, q, Wb + BQ, nullptr, nullptr, MS, D, D, 1.f, 0, 0, 0);
    gemm_bt<1, 1, 0><<<dim3(D / 128, MS / 128), blk, 0, stream>>>(key_,  Wb + WK, k, Wb + BK, nullptr, nullptr, MS, D, D, 1.f, 0, 0, 0);
    gemm_bt<1, 1, 0><<<dim3(D / 128, MS / 128), blk, 0, stream>>>(value, Wb + WV, v, Wb + BV, nullptr, nullptr, MS, D, D, 1.f, 0, 0, 0);
    // 2. vT = transpose(v) per batch; v (front of d_out) dead afterwards
    transpose2d<<<dim3(D / 32, S / 32, Bc), dim3(32, 8), 0, stream>>>(v, vT, S, D);
    // 3-5. attention
    if (batched) {
        gemm_bt<2, 0, 0><<<dim3(S / 128, S / 128, Bc), blk, 0, stream>>>(q, k, P, nullptr, nullptr, nullptr, S, S, D, scale, SD, SD, SS);
        softmax_inplace<<<dim3(MS), blk, 0, stream>>>(P, S);
        gemm_bt<0, 0, 0><<<dim3(D / 128, S / 128, Bc), blk, 0, stream>>>(P, vT, att, nullptr, nullptr, nullptr, S, D, S, 1.f, SS, SD, SD);
    } else {
        for (int z = 0; z < Bc; ++z) {
            gemm_bt<2, 0, 0><<<dim3(S / 128, S / 128), blk, 0, stream>>>(q + (size_t)z * SD, k + (size_t)z * SD, P,
                                                                          nullptr, nullptr, nullptr, S, S, D, scale, 0, 0, 0);
            softmax_inplace<<<dim3(S), blk, 0, stream>>>(P, S);
            gemm_bt<0, 0, 0><<<dim3(D / 128, S / 128), blk, 0, stream>>>(P, vT + (size_t)z * SD, att + (size_t)z * SD,
                                                                          nullptr, nullptr, nullptr, S, D, S, 1.f, 0, 0, 0);
        }
    }
    // 6. h = relu(att @ Wg1^T + bg1)   (att bf16 now; h overlays k)
    gemm_bt<3, 0, 0><<<dim3(D / 128, MS / 128), blk, 0, stream>>>(att, Wb + WG1, h, Wb + BG1, nullptr, nullptr, MS, D, D, 1.f, 0, 0, 0);
    // 7. out = sigmoid(sigmoid(h @ Wg2^T + bg2)) * att * ts   (aux = bf16 att; C = f32 d_out)
    gemm_bt<4, 0, 1><<<dim3(D / 128, MS / 128), blk, 0, stream>>>(h, Wb + WG2, d_out, Wb + BG2, att, Wb + TSO, MS, D, D, 1.f, 0, 0, 0);
}

// Round 5
// 374.105 us; speedup vs baseline: 2.1758x; 1.0015x over previous
//
#include <hip/hip_runtime.h>

typedef unsigned short ushort_t;
typedef __bf16 bf16x8 __attribute__((ext_vector_type(8)));
typedef float f32x4 __attribute__((ext_vector_type(4)));
typedef short short8 __attribute__((ext_vector_type(8)));

#define SBAR()   asm volatile("s_barrier" ::: "memory")
#define WAITV0() asm volatile("s_waitcnt vmcnt(0)" ::: "memory")
#define WAITV2() asm volatile("s_waitcnt vmcnt(2)" ::: "memory")
#define WAITV4() asm volatile("s_waitcnt vmcnt(4)" ::: "memory")
#define WAITV6() asm volatile("s_waitcnt vmcnt(6)" ::: "memory")
#define WAITL0() asm volatile("s_waitcnt lgkmcnt(0)" ::: "memory")

__device__ __forceinline__ float bf2f(unsigned short u) {
    union { unsigned int i; float f; } v; v.i = ((unsigned int)u) << 16; return v.f;
}
__device__ __forceinline__ unsigned short f2bf(float f) {
    union { float f; unsigned int i; } v; v.f = f;
    unsigned int r = v.i + 0x7fffu + ((v.i >> 16) & 1u);
    return (unsigned short)(r >> 16);
}
__device__ __forceinline__ float sigm(float x) { return 1.0f / (1.0f + __expf(-x)); }

__device__ __forceinline__ void async_copy16(const ushort_t* src, ushort_t* dst_lds) {
    __builtin_amdgcn_global_load_lds(
        (const __attribute__((address_space(1))) void*)src,
        (__attribute__((address_space(3))) void*)dst_lds,
        16, 0, 0);
}

// ---- param conversion: 5 W (768x768) + 5 bias (768) + ts (768), f32 -> bf16, fixed layout ----
#define WSEG 589824           // 768*768
#define NWALL 2949120         // 5*WSEG
#define NTOT 2953728          // + 6*768
__global__ __launch_bounds__(256)
void convert_params(const float* __restrict__ Wq, const float* __restrict__ Wk,
                    const float* __restrict__ Wv, const float* __restrict__ Wg1,
                    const float* __restrict__ Wg2, const float* __restrict__ bq,
                    const float* __restrict__ bk, const float* __restrict__ bv,
                    const float* __restrict__ bg1, const float* __restrict__ bg2,
                    const float* __restrict__ ts, ushort_t* __restrict__ dst)
{
    int i = (blockIdx.x * 256 + threadIdx.x) * 8;
    if (i >= NTOT) return;
    const float* src; int off;
    if (i < NWALL) {
        int wi = i / WSEG; off = i - wi * WSEG;
        src = (wi == 0) ? Wq : (wi == 1) ? Wk : (wi == 2) ? Wv : (wi == 3) ? Wg1 : Wg2;
    } else {
        int j = i - NWALL; int bi = j / 768; off = j - bi * 768;
        src = (bi == 0) ? bq : (bi == 1) ? bk : (bi == 2) ? bv : (bi == 3) ? bg1 : (bi == 4) ? bg2 : ts;
    }
    float4 a = *(const float4*)(src + off);
    float4 b = *(const float4*)(src + off + 4);
    short8 o;
    o[0] = (short)f2bf(a.x); o[1] = (short)f2bf(a.y); o[2] = (short)f2bf(a.z); o[3] = (short)f2bf(a.w);
    o[4] = (short)f2bf(b.x); o[5] = (short)f2bf(b.y); o[6] = (short)f2bf(b.z); o[7] = (short)f2bf(b.w);
    *(short8*)(dst + i) = o;
}

// C[M,N] = A[M,K] @ B[N,K]^T (+ epilogue), optionally batched (M = rows per batch).
// Double-buffered LDS, counted-vmcnt pipeline (stage t+1 before waiting on t), raw s_barrier.
// B always bf16. AF32: A is f32 (reg-staged f32x16/thread + cvt + ds_write). CF32: f32 store.
// EPI: 0=plain, 1=+bias, 2=*scale, 3=+bias+relu, 4=gate: sigmoid(sigmoid(x+bias))*aux*ts
// Requires gridDim.x*gridDim.y*gridDim.z % 8 == 0, K%32==0.
template<int EPI, int AF32, int CF32>
__global__ __launch_bounds__(256, 2)
void gemm_bt(const void* __restrict__ Av, const ushort_t* __restrict__ B,
             void* __restrict__ Cv, const ushort_t* __restrict__ bias,
             const ushort_t* __restrict__ aux, const ushort_t* __restrict__ ts,
             int M, int N, int K, float scale,
             long long batchA, long long batchB, long long batchC)
{
    __shared__ __align__(16) ushort_t As[2][128 * 32];
    __shared__ __align__(16) ushort_t Bs[2][128 * 32];
    const int tid  = threadIdx.x;
    const int lane = tid & 63;
    const int wave = tid >> 6;
    const int wr = wave >> 1, wc = wave & 1;

    // XCD-aware bijective swizzle over the full flat grid (nwg % 8 == 0)
    const int gx = gridDim.x, gy = gridDim.y;
    const int nwg = gx * gy * gridDim.z;
    int fid = (blockIdx.z * gy + blockIdx.y) * gx + blockIdx.x;
    fid = (fid & 7) * (nwg >> 3) + (fid >> 3);
    const int bz  = fid / (gx * gy);
    const int rem = fid - bz * (gx * gy);
    const int by  = rem / gx;
    const int bx  = rem - by * gx;
    const int row0 = by * 128;
    const int col0 = bx * 128;

    f32x4 acc[4][4] = {};

    // bf16 staging: 256 threads x 16B = 64 rows of 32 bf16 per inst
    const int srow = tid >> 2;
    const int scol = (tid & 3) * 8;
    const ushort_t* ga0 = (const ushort_t*)Av + batchA * bz + (size_t)(row0 + srow) * K + scol;
    const ushort_t* gb0 = B + batchB * bz + (size_t)(col0 + srow) * K + scol;
    // f32-A staging: thread t -> row t>>1, col half (t&1)*16; 16 f32 per thread
    const int arow_s = tid >> 1;
    const int acol_s = (tid & 1) * 16;
    const float* gaf = (const float*)Av + batchA * bz + (size_t)(row0 + arow_s) * K + acol_s;

    const int kop  = (lane >> 4) * 8;
    const int arow = wr * 64 + (lane & 15);
    const int brow = wc * 64 + (lane & 15);

    const int NT = K >> 5;

    if (AF32) {
        // prologue: A-regs for t0 (4 loads), B-stage t0 (2 loads)
        float4 fa0 = *(const float4*)(gaf);
        float4 fa1 = *(const float4*)(gaf + 4);
        float4 fa2 = *(const float4*)(gaf + 8);
        float4 fa3 = *(const float4*)(gaf + 12);
        async_copy16(gb0,                  Bs[0] + tid * 8);
        async_copy16(gb0 + (size_t)64 * K, Bs[0] + 2048 + tid * 8);

        for (int t = 0; t < NT; ++t) {
            const int cur = t & 1;
            WAITV2();   // fa(t) landed; B(t) (2 loads) may still fly
            short8 p0, p1;
            p0[0] = (short)f2bf(fa0.x); p0[1] = (short)f2bf(fa0.y);
            p0[2] = (short)f2bf(fa0.z); p0[3] = (short)f2bf(fa0.w);
            p0[4] = (short)f2bf(fa1.x); p0[5] = (short)f2bf(fa1.y);
            p0[6] = (short)f2bf(fa1.z); p0[7] = (short)f2bf(fa1.w);
            p1[0] = (short)f2bf(fa2.x); p1[1] = (short)f2bf(fa2.y);
            p1[2] = (short)f2bf(fa2.z); p1[3] = (short)f2bf(fa2.w);
            p1[4] = (short)f2bf(fa3.x); p1[5] = (short)f2bf(fa3.y);
            p1[6] = (short)f2bf(fa3.z); p1[7] = (short)f2bf(fa3.w);
            *(short8*)(As[cur] + arow_s * 32 + acol_s)     = p0;
            *(short8*)(As[cur] + arow_s * 32 + acol_s + 8) = p1;
            if (t + 1 < NT) {
                const int k1 = (t + 1) * 32;
                fa0 = *(const float4*)(gaf + k1);
                fa1 = *(const float4*)(gaf + k1 + 4);
                fa2 = *(const float4*)(gaf + k1 + 8);
                fa3 = *(const float4*)(gaf + k1 + 12);
                async_copy16(gb0 + k1,                  Bs[cur ^ 1] + tid * 8);
                async_copy16(gb0 + (size_t)64 * K + k1, Bs[cur ^ 1] + 2048 + tid * 8);
                WAITV6();   // B(t) landed; fa(t+1)+B(t+1) (6 loads) may fly
            } else {
                WAITV0();
            }
            WAITL0();       // ds_writes visible
            SBAR();
            bf16x8 af[4], bfr[4];
            #pragma unroll
            for (int m = 0; m < 4; ++m)
                af[m] = *(const bf16x8*)(As[cur] + (arow + m * 16) * 32 + kop);
            #pragma unroll
            for (int n = 0; n < 4; ++n)
                bfr[n] = *(const bf16x8*)(Bs[cur] + (brow + n * 16) * 32 + kop);
            #pragma unroll
            for (int m = 0; m < 4; ++m)
                #pragma unroll
                for (int n = 0; n < 4; ++n)
                    acc[m][n] = __builtin_amdgcn_mfma_f32_16x16x32_bf16(af[m], bfr[n], acc[m][n], 0, 0, 0);
            SBAR();
        }
    } else {
        // prologue: stage t0 (4 loads)
        async_copy16(ga0,                  As[0] + tid * 8);
        async_copy16(ga0 + (size_t)64 * K, As[0] + 2048 + tid * 8);
        async_copy16(gb0,                  Bs[0] + tid * 8);
        async_copy16(gb0 + (size_t)64 * K, Bs[0] + 2048 + tid * 8);

        for (int t = 0; t < NT; ++t) {
            const int cur = t & 1;
            if (t + 1 < NT) {
                const int k1 = (t + 1) * 32;
                async_copy16(ga0 + k1,                  As[cur ^ 1] + tid * 8);
                async_copy16(ga0 + (size_t)64 * K + k1, As[cur ^ 1] + 2048 + tid * 8);
                async_copy16(gb0 + k1,                  Bs[cur ^ 1] + tid * 8);
                async_copy16(gb0 + (size_t)64 * K + k1, Bs[cur ^ 1] + 2048 + tid * 8);
                WAITV4();   // tile t landed; tile t+1 (4 loads) in flight
            } else {
                WAITV0();
            }
            SBAR();
            bf16x8 af[4], bfr[4];
            #pragma unroll
            for (int m = 0; m < 4; ++m)
                af[m] = *(const bf16x8*)(As[cur] + (arow + m * 16) * 32 + kop);
            #pragma unroll
            for (int n = 0; n < 4; ++n)
                bfr[n] = *(const bf16x8*)(Bs[cur] + (brow + n * 16) * 32 + kop);
            #pragma unroll
            for (int m = 0; m < 4; ++m)
                #pragma unroll
                for (int n = 0; n < 4; ++n)
                    acc[m][n] = __builtin_amdgcn_mfma_f32_16x16x32_bf16(af[m], bfr[n], acc[m][n], 0, 0, 0);
            SBAR();
        }
    }

    // epilogue: C/D layout col=lane&15, row=(lane>>4)*4+reg
    const int r0 = row0 + wr * 64 + (lane >> 4) * 4;
    const int c0 = col0 + wc * 64 + (lane & 15);
    #pragma unroll
    for (int m = 0; m < 4; ++m) {
        #pragma unroll
        for (int n = 0; n < 4; ++n) {
            const int col = c0 + n * 16;
            #pragma unroll
            for (int r = 0; r < 4; ++r) {
                const int row = r0 + m * 16 + r;
                float val = acc[m][n][r];
                if (EPI == 1) {
                    val += bf2f(bias[col]);
                } else if (EPI == 2) {
                    val *= scale;
                } else if (EPI == 3) {
                    val += bf2f(bias[col]);
                    val = fmaxf(val, 0.0f);
                } else if (EPI == 4) {
                    val += bf2f(bias[col]);
                    float g  = sigm(val);
                    float gg = sigm(g);
                    val = gg * bf2f(aux[batchC * bz + (size_t)row * N + col]) * bf2f(ts[col]);
                }
                if (CF32) ((float*)Cv)[batchC * bz + (size_t)row * N + col] = val;
                else      ((ushort_t*)Cv)[batchC * bz + (size_t)row * N + col] = f2bf(val);
            }
        }
    }
}

// in-place row softmax: P is [rows][S] bf16, one block (256 thr) per row, S=2048
__global__ __launch_bounds__(256)
void softmax_inplace(ushort_t* __restrict__ P, int S)
{
    const size_t row = blockIdx.x;
    ushort_t* p = P + row * (size_t)S;
    const int tid = threadIdx.x;
    const int lane = tid & 63, wave = tid >> 6;

    short8 raw = *(const short8*)(p + tid * 8);
    float x[8];
    #pragma unroll
    for (int j = 0; j < 8; ++j) x[j] = bf2f((unsigned short)raw[j]);

    float mx = x[0];
    #pragma unroll
    for (int j = 1; j < 8; ++j) mx = fmaxf(mx, x[j]);
    #pragma unroll
    for (int o = 32; o > 0; o >>= 1) mx = fmaxf(mx, __shfl_xor(mx, o));
    __shared__ float redm[4], reds[4];
    if (lane == 0) redm[wave] = mx;
    __syncthreads();
    mx = fmaxf(fmaxf(redm[0], redm[1]), fmaxf(redm[2], redm[3]));

    float s = 0.f;
    #pragma unroll
    for (int j = 0; j < 8; ++j) { x[j] = __expf(x[j] - mx); s += x[j]; }
    #pragma unroll
    for (int o = 32; o > 0; o >>= 1) s += __shfl_xor(s, o);
    if (lane == 0) reds[wave] = s;
    __syncthreads();
    s = reds[0] + reds[1] + reds[2] + reds[3];
    const float inv = 1.0f / s;

    short8 outv;
    #pragma unroll
    for (int j = 0; j < 8; ++j) outv[j] = (short)f2bf(x[j] * inv);
    *(short8*)(p + tid * 8) = outv;
}

// VT[z][c][r] = V[z][r][c];  grid (C/32, R/32, Z), block (32,8). bf16.
__global__ __launch_bounds__(256)
void transpose2d(const ushort_t* __restrict__ V, ushort_t* __restrict__ VT, int R, int Ccols)
{
    __shared__ ushort_t t[32][33];
    const size_t zoff = (size_t)blockIdx.z * R * Ccols;
    const int tx = threadIdx.x, ty = threadIdx.y;
    const int c = blockIdx.x * 32 + tx;
    const int rbase = blockIdx.y * 32;
    #pragma unroll
    for (int i = 0; i < 4; ++i)
        t[ty + i * 8][tx] = V[zoff + (size_t)(rbase + ty + i * 8) * Ccols + c];
    __syncthreads();
    const int r = rbase + tx;
    const int cbase = blockIdx.x * 32;
    #pragma unroll
    for (int i = 0; i < 4; ++i)
        VT[zoff + (size_t)(cbase + ty + i * 8) * R + r] = t[tx][ty + i * 8];
}

extern "C" void kernel_launch(void* const* d_in, const int* in_sizes, int n_in,
                              void* d_out, int out_size, void* d_ws, size_t ws_size,
                              hipStream_t stream)
{
    (void)in_sizes; (void)n_in; (void)out_size;
    const float* query = (const float*)d_in[0];
    const float* key_  = (const float*)d_in[1];
    const float* value = (const float*)d_in[2];
    const float* Wq  = (const float*)d_in[3];
    const float* bq  = (const float*)d_in[4];
    const float* Wk  = (const float*)d_in[5];
    const float* bk  = (const float*)d_in[6];
    const float* Wv  = (const float*)d_in[7];
    const float* bv  = (const float*)d_in[8];
    const float* Wg1 = (const float*)d_in[9];
    const float* bg1 = (const float*)d_in[10];
    const float* Wg2 = (const float*)d_in[11];
    const float* bg2 = (const float*)d_in[12];
    const float* tsc = (const float*)d_in[13];

    const int S = 2048, D = 768, Bc = 8;
    const int MS = Bc * S;                     // 16384
    const long long SD = (long long)S * D;     // 1,572,864 elems per batch
    const long long SS = (long long)S * S;     // 4,194,304 elems per batch

    // ws layout (bytes):
    //   q/att @0 (25.2M) | k/h @25.2M (25.2M) | vT @50.3M (25.2M) | Wb @75.5M (5.9M) | P @81.4M
    char* ws = (char*)d_ws;
    ushort_t* q   = (ushort_t*)(ws);
    ushort_t* att = q;                         // PV(z) overwrites q(z) after scores(z) consumed it
    ushort_t* k   = (ushort_t*)(ws + 25165824ll);
    ushort_t* h   = k;                         // k dead after scores
    ushort_t* vT  = (ushort_t*)(ws + 50331648ll);
    ushort_t* Wb  = (ushort_t*)(ws + 75497472ll);
    ushort_t* P   = (ushort_t*)(ws + 81404928ll);
    ushort_t* v   = (ushort_t*)d_out;          // bf16 v in front half of d_out until transpose

    const int WQ = 0, WK = 589824, WV = 1179648, WG1 = 1769472, WG2 = 2359296;
    const int BQ = 2949120, BK = 2949888, BV = 2950656, BG1 = 2951424, BG2 = 2952192, TSO = 2952960;

    const dim3 blk(256);
    const float scale = 0.03608439182435161f; // 1/sqrt(768)
    const bool batched = ws_size >= 148513792ull;

    // 0. convert params to bf16
    convert_params<<<dim3((NTOT / 8 + 255) / 256), blk, 0, stream>>>(
        Wq, Wk, Wv, Wg1, Wg2, bq, bk, bv, bg1, bg2, tsc, Wb);
    // 1. projections (A = f32 inputs)
    gemm_bt<1, 1, 0><<<dim3(D / 128, MS / 128), blk, 0, stream>>>(query, Wb + WQ, q, Wb + BQ, nullptr, nullptr, MS, D, D, 1.f, 0, 0, 0);
    gemm_bt<1, 1, 0><<<dim3(D / 128, MS / 128), blk, 0, stream>>>(key_,  Wb + WK, k, Wb + BK, nullptr, nullptr, MS, D, D, 1.f, 0, 0, 0);
    gemm_bt<1, 1, 0><<<dim3(D / 128, MS / 128), blk, 0, stream>>>(value, Wb + WV, v, Wb + BV, nullptr, nullptr, MS, D, D, 1.f, 0, 0, 0);
    // 2. vT = transpose(v) per batch; v (front of d_out) dead afterwards
    transpose2d<<<dim3(D / 32, S / 32, Bc), dim3(32, 8), 0, stream>>>(v, vT, S, D);
    // 3-5. attention
    if (batched) {
        gemm_bt<2, 0, 0><<<dim3(S / 128, S / 128, Bc), blk, 0, stream>>>(q, k, P, nullptr, nullptr, nullptr, S, S, D, scale, SD, SD, SS);
        softmax_inplace<<<dim3(MS), blk, 0, stream>>>(P, S);
        gemm_bt<0, 0, 0><<<dim3(D / 128, S / 128, Bc), blk, 0, stream>>>(P, vT, att, nullptr, nullptr, nullptr, S, D, S, 1.f, SS, SD, SD);
    } else {
        for (int z = 0; z < Bc; ++z) {
            gemm_bt<2, 0, 0><<<dim3(S / 128, S / 128), blk, 0, stream>>>(q + (size_t)z * SD, k + (size_t)z * SD, P,
                                                                          nullptr, nullptr, nullptr, S, S, D, scale, 0, 0, 0);
            softmax_inplace<<<dim3(S), blk, 0, stream>>>(P, S);
            gemm_bt<0, 0, 0><<<dim3(D / 128, S / 128), blk, 0, stream>>>(P, vT + (size_t)z * SD, att + (size_t)z * SD,
                                                                          nullptr, nullptr, nullptr, S, D, S, 1.f, 0, 0, 0);
        }
    }
    // 6. h = relu(att @ Wg1^T + bg1)   (att bf16; h overlays k)
    gemm_bt<3, 0, 0><<<dim3(D / 128, MS / 128), blk, 0, stream>>>(att, Wb + WG1, h, Wb + BG1, nullptr, nullptr, MS, D, D, 1.f, 0, 0, 0);
    // 7. out = sigmoid(sigmoid(h @ Wg2^T + bg2)) * att * ts   (aux = bf16 att; C = f32 d_out)
    gemm_bt<4, 0, 1><<<dim3(D / 128, MS / 128), blk, 0, stream>>>(h, Wb + WG2, d_out, Wb + BG2, att, Wb + TSO, MS, D, D, 1.f, 0, 0, 0);
}